// Round 3
// 238.718 us; speedup vs baseline: 1.0234x; 1.0234x over previous
//
#include <hip/hip_runtime.h>

typedef unsigned short u16;
typedef __bf16 bf8 __attribute__((ext_vector_type(8)));
typedef float f4 __attribute__((ext_vector_type(4)));

#define E_EDGES 32768
#define N_NODES 4096
// col layout of w (WNUM=6400): A[u<64][w<64] @0, B[u<64][w<16] @4096, C[u<16][w<16] @5120, D[u<16][w<64] @5376
// k4-group g covers tiles 4g..4g+3; ranges: A g<64, B 64..79, C 80..83, D 84..99 (all 4-aligned)
#define N0_CONST 0.1118033988749895f       // sqrt(1/80); also equals N1*INV_SQRT3
#define INV_SQRT3_CONST 0.5773502691896258f

// rule #18 fence: nothing may be scheduled across (pins MFMA + lgkmcnt waits on the
// correct side of inline-asm waitcnt / raw s_barrier; hipcc otherwise sinks them).
#define SB0() __builtin_amdgcn_sched_barrier(0)

__device__ __forceinline__ u16 f2bf(float f) {
    unsigned u = __float_as_uint(f);
    u += 0x7FFFu + ((u >> 16) & 1u);   // RNE
    return (u16)(u >> 16);
}

__device__ __forceinline__ void gld16(const u16* g, u16* l) {
    __builtin_amdgcn_global_load_lds((const __attribute__((address_space(1))) void*)g,
                                     (__attribute__((address_space(3))) void*)l, 16, 0, 0);
}

__device__ __forceinline__ void gld16f(const float* g, float* l) {
    __builtin_amdgcn_global_load_lds((const __attribute__((address_space(1))) void*)g,
                                     (__attribute__((address_space(3))) void*)l, 16, 0, 0);
}

// Weight prep + src-degree histogram, one launch:
//  blocks 0..399:   w2s fragment-order swizzle (tile = 4KB contiguous)
//  blocks 400..415: w1t[c*128+k] = bf16(W1[k*128+c])
//  blocks 416..543: deg histogram over edge src (deg pre-zeroed by memsetAsync)
__global__ __launch_bounds__(256) void k_prep(const float* __restrict__ W2, const float* __restrict__ W1,
                                              const int* __restrict__ edge_index,
                                              u16* __restrict__ w2s, u16* __restrict__ w1t,
                                              int* __restrict__ deg) {
    int b = blockIdx.x;
    int tid = threadIdx.x;
    if (b < 400) {
        int ks = tid >> 6, l = tid & 63;
        int el = l & 15, q4 = l >> 4;
        int c = b * 16 + el;
        u16 tmp[8];
#pragma unroll
        for (int j = 0; j < 8; j++) {
            int k = ks * 32 + q4 * 8 + j;
            tmp[j] = f2bf(W2[(size_t)k * 6400 + c]);
        }
        *(uint4*)(w2s + b * 2048 + ks * 512 + l * 8) = *(uint4*)tmp;
    } else if (b < 416) {
        int t = (b - 400) * 256 + tid;
#pragma unroll
        for (int i = 0; i < 4; i++) {
            int idx = t * 4 + i;                // idx = c*128 + k
            int c = idx >> 7, k = idx & 127;
            w1t[idx] = f2bf(W1[k * 128 + c]);
        }
    } else {
        int t = (b - 416) * 256 + tid;          // 128 blocks * 256 = 32768 = E
        atomicAdd(&deg[edge_index[t]], 1);
    }
}

// Exclusive scan of deg[4096] -> ptr[0..4096] and cursor copy. 1 block, 64 threads.
__global__ void k_scan(const int* __restrict__ deg, int* __restrict__ ptr, int* __restrict__ cursor) {
    int t = threadIdx.x;           // 0..63
    int base = t * 64;
    int s = 0;
    for (int i = 0; i < 64; i++) s += deg[base + i];
    int x = s;
#pragma unroll
    for (int d = 1; d < 64; d <<= 1) {
        int y = __shfl_up(x, d, 64);
        if (t >= d) x += y;
    }
    int run = x - s;               // exclusive prefix
    for (int i = 0; i < 64; i++) {
        ptr[base + i] = run;
        cursor[base + i] = run;
        run += deg[base + i];
    }
    if (t == 63) ptr[4096] = run;
}

// h = relu(edge_attr @ W1 + b1), stored bf16 [E][128]; also fills CSR edge-id list via cursor
__global__ __launch_bounds__(256) void k_h(const float* __restrict__ ea,
                                           const u16* __restrict__ w1t,
                                           const float* __restrict__ b1,
                                           const int* __restrict__ edge_index,
                                           int* __restrict__ cursor,
                                           int* __restrict__ eids,
                                           u16* __restrict__ h) {
    __shared__ alignas(16) u16 ea_s[64][128];
    int tid = threadIdx.x;
    int e0 = blockIdx.x * 64;
    if (tid < 64) {                // CSR fill for this block's 64 edges
        int ge = e0 + tid;
        int s = edge_index[ge];
        int pos = atomicAdd(&cursor[s], 1);
        eids[pos] = ge;
    }
    {
        int e = tid >> 2, q = tid & 3;
        const float4* src = (const float4*)(ea + (size_t)(e0 + e) * 128 + q * 32);
#pragma unroll
        for (int i = 0; i < 8; i++) {
            float4 f = src[i];
            int c = q * 32 + i * 4;
            ea_s[e][c + 0] = f2bf(f.x); ea_s[e][c + 1] = f2bf(f.y);
            ea_s[e][c + 2] = f2bf(f.z); ea_s[e][c + 3] = f2bf(f.w);
        }
    }
    __syncthreads();
    int lane = tid & 63, wave = tid >> 6;
    int el = lane & 15, q4 = lane >> 4;
    f4 acc[4][2];
#pragma unroll
    for (int m = 0; m < 4; m++)
#pragma unroll
        for (int nt = 0; nt < 2; nt++) acc[m][nt] = (f4){0.f, 0.f, 0.f, 0.f};
#pragma unroll
    for (int ks = 0; ks < 4; ks++) {
        bf8 a[4], b[2];
#pragma unroll
        for (int m = 0; m < 4; m++) a[m] = *(const bf8*)&ea_s[m * 16 + el][ks * 32 + q4 * 8];
#pragma unroll
        for (int nt = 0; nt < 2; nt++) {
            int n = wave * 32 + nt * 16 + el;
            b[nt] = *(const bf8*)(w1t + n * 128 + ks * 32 + q4 * 8);
        }
#pragma unroll
        for (int m = 0; m < 4; m++)
#pragma unroll
            for (int nt = 0; nt < 2; nt++)
                acc[m][nt] = __builtin_amdgcn_mfma_f32_16x16x32_bf16(a[m], b[nt], acc[m][nt], 0, 0, 0);
    }
#pragma unroll
    for (int m = 0; m < 4; m++)
#pragma unroll
        for (int nt = 0; nt < 2; nt++) {
            int n = wave * 32 + nt * 16 + el;
            float bias = b1[n];
#pragma unroll
            for (int r = 0; r < 4; r++) {
                int e = e0 + m * 16 + q4 * 4 + r;
                float v = fmaxf(acc[m][nt][r] + bias, 0.f);
                h[(size_t)e * 128 + n] = f2bf(v);
            }
        }
}

// Fused: w = h@W2+b2 tile-by-tile -> contraction -> tp[E][112].
// T3+T4 pipeline: pair (2 tiles, 8KB) granularity, 4 LDS pair-buffers, depth-3 prefetch.
// Per pair per wave exactly 3 VMEM ops (2 tile gld16 + 1 FULL-WAVE b2 gld16) so counted
// s_waitcnt vmcnt(6) = "2 newer pairs in flight" guarantees pair p landed. ONE raw s_barrier
// per pair, never a vmcnt(0) drain in steady state. Sync points fenced with sched_barrier(0)
// (rule #18). The b2 stage uses ALL 64 lanes (1KB buffer) with clamped per-lane source:
// global_load_lds's LDS write is wave-uniform-base + lane*16B for the full wave, so a
// lane-masked DMA can overflow its buffer (rounds 1-2 trampled sT -> deterministic absmax 3).
__global__ __launch_bounds__(256, 2) void k_main(const u16* __restrict__ w2s,
                                                 const u16* __restrict__ hgl,
                                                 const float* __restrict__ b2,
                                                 const float* __restrict__ node_attr,
                                                 const int* __restrict__ edge_index,
                                                 const float* __restrict__ edge_sh,
                                                 float* __restrict__ tp) {
    __shared__ alignas(16) union {
        u16 h[64][128];                       // 16384 B (prologue)
        u16 stage[4][2][2048];                // 32768 B (loop: [buf][tileInPair][4KB])
    } ovl;
    __shared__ alignas(16) float b2s[4][256]; // staged bias: 1KB/buf (full-wave DMA footprint);
                                              // only [0..32) consumed = b2[p*32 .. p*32+32)
    __shared__ float sT[64][66];              // s[u][e]; epilogue: out0[e][c] (stride 66)
    __shared__ float vT[3][16][66];           // v[i][u][e]; epilogue: out1 flat [e*48+cr]
    __shared__ float pT[16][66];              // INV_SQRT3*(v.sh1)[u][e]
    __shared__ float sh0_s[64];
    __shared__ float sh1_s[3][64];
    __shared__ int dst_s[64];

    int tid = threadIdx.x;
    int e0 = blockIdx.x * 64;

    // phase 1: edge meta (+ b2s zero-init: harmless if DMA lands, correct if bias==0 path ever skipped)
    {
        float4 z = {0.f, 0.f, 0.f, 0.f};
        *(float4*)&b2s[tid >> 6][(tid & 63) * 4] = z;
    }
    if (tid < 64) {
        int ge = e0 + tid;
        dst_s[tid] = edge_index[E_EDGES + ge];
        float4 sh = *(const float4*)(edge_sh + (size_t)ge * 4);
        sh0_s[tid] = sh.x; sh1_s[0][tid] = sh.y; sh1_s[1][tid] = sh.z; sh1_s[2][tid] = sh.w;
    }
    __syncthreads();

    // phase 2: node features (transposed into LDS) + h tile into ovl.h
    {
        int e = tid >> 2, q = tid & 3;
        int dst = dst_s[e];
        const float* xp = node_attr + (size_t)dst * 112;
#pragma unroll
        for (int i = 0; i < 4; i++) {
            float4 f = *(const float4*)(xp + q * 16 + i * 4);
            int u = q * 16 + i * 4;
            sT[u + 0][e] = f.x; sT[u + 1][e] = f.y; sT[u + 2][e] = f.z; sT[u + 3][e] = f.w;
        }
        float vv[12];
#pragma unroll
        for (int i = 0; i < 3; i++) {
            float4 f = *(const float4*)(xp + 64 + q * 12 + i * 4);
            vv[i * 4 + 0] = f.x; vv[i * 4 + 1] = f.y; vv[i * 4 + 2] = f.z; vv[i * 4 + 3] = f.w;
        }
        float s1x = sh1_s[0][e], s1y = sh1_s[1][e], s1z = sh1_s[2][e];
#pragma unroll
        for (int u = 0; u < 4; u++) {
            float xa = vv[u * 3 + 0], xb = vv[u * 3 + 1], xc = vv[u * 3 + 2];
            int uu = q * 4 + u;
            vT[0][uu][e] = xa; vT[1][uu][e] = xb; vT[2][uu][e] = xc;
            pT[uu][e] = INV_SQRT3_CONST * (xa * s1x + xb * s1y + xc * s1z);
        }
        const uint4* hsrc = (const uint4*)(hgl + (size_t)(e0 + e) * 128) + q * 4;
        uint4* hdst = (uint4*)(&ovl.h[e][q * 32]);
#pragma unroll
        for (int i = 0; i < 4; i++) hdst[i] = hsrc[i];
    }
    __syncthreads();

    int lane = tid & 63, wave = tid >> 6;
    int el = lane & 15, q4 = lane >> 4;
    int eln = wave * 16 + el;                 // this wave's edge for this lane

    // B-fragments: wave owns n-tile = its 16 edges -> only 4 bf8 (16 VGPRs)
    bf8 hb[4];
#pragma unroll
    for (int ks = 0; ks < 4; ks++)
        hb[ks] = *(const bf8*)&ovl.h[eln][ks * 32 + q4 * 8];
    float sh0n = sh0_s[eln];
    __syncthreads();   // h region free -> becomes stage buffers (full drain; vmcnt=0 here)

    f4 acc0[4], accB, accC[3];
#pragma unroll
    for (int j = 0; j < 4; j++) acc0[j] = (f4){0.f, 0.f, 0.f, 0.f};
    accB = (f4){0.f, 0.f, 0.f, 0.f};
#pragma unroll
    for (int i = 0; i < 3; i++) accC[i] = (f4){0.f, 0.f, 0.f, 0.f};

    auto mfma4 = [&](const u16* st, float4 bb) -> f4 {
        const u16* sp = st + lane * 8;
        bf8 a0 = *(const bf8*)(sp + 0);
        bf8 a1 = *(const bf8*)(sp + 512);
        bf8 a2 = *(const bf8*)(sp + 1024);
        bf8 a3 = *(const bf8*)(sp + 1536);
        f4 w = (f4){bb.x, bb.y, bb.z, bb.w};
        w = __builtin_amdgcn_mfma_f32_16x16x32_bf16(a0, hb[0], w, 0, 0, 0);
        w = __builtin_amdgcn_mfma_f32_16x16x32_bf16(a1, hb[1], w, 0, 0, 0);
        w = __builtin_amdgcn_mfma_f32_16x16x32_bf16(a2, hb[2], w, 0, 0, 0);
        w = __builtin_amdgcn_mfma_f32_16x16x32_bf16(a3, hb[3], w, 0, 0, 0);
        return w;
    };

    // issue one pair's 3 VMEM ops (identical count & order on every wave -> vmcnt math holds)
    auto issue_pair = [&](int pn) {
        const u16* gp = w2s + (size_t)pn * 4096 + tid * 8;
        int bn = pn & 3;
        gld16(gp, &ovl.stage[bn][0][tid * 8]);
        gld16(gp + 2048, &ovl.stage[bn][1][tid * 8]);
        // full-wave bias stage: lanes 0..7 carry the pair's 32 floats; lanes 8..63 are
        // in-bounds clamped filler landing in b2s[bn][32..256) (never consumed).
        int off = pn * 32 + lane * 4;
        off = off < 6396 ? off : 6396;
        gld16f(b2 + off, &b2s[bn][lane * 4]);
    };

    auto consume_pair = [&](int buf, f4& wA, f4& wB) {
        float4 bb0 = *(const float4*)&b2s[buf][q4 * 4];
        float4 bb1 = *(const float4*)&b2s[buf][16 + q4 * 4];
        wA = mfma4(&ovl.stage[buf][0][0], bb0);
        wB = mfma4(&ovl.stage[buf][1][0], bb1);
    };

    auto contract = [&](int g, const f4& w0, const f4& w1, const f4& w2t, const f4& w3) {
        if (g < 64) {                         // A: u = g, out0 col-blocks j*16
            float sv = sh0n * sT[g][eln];
            acc0[0] += sv * w0; acc0[1] += sv * w1; acc0[2] += sv * w2t; acc0[3] += sv * w3;
        } else if (g < 80) {                  // B: u = 4*(g-64)+j
            int u0 = (g - 64) * 4;
            accB += sT[u0 + 0][eln] * w0 + sT[u0 + 1][eln] * w1
                  + sT[u0 + 2][eln] * w2t + sT[u0 + 3][eln] * w3;
        } else if (g < 84) {                  // C: u = 4*(g-80)+j
            int u0 = (g - 80) * 4;
#pragma unroll
            for (int i = 0; i < 3; i++)
                accC[i] += vT[i][u0 + 0][eln] * w0 + vT[i][u0 + 1][eln] * w1
                         + vT[i][u0 + 2][eln] * w2t + vT[i][u0 + 3][eln] * w3;
        } else {                              // D: u = g-84
            float pv = pT[g - 84][eln];
            acc0[0] += pv * w0; acc0[1] += pv * w1; acc0[2] += pv * w2t; acc0[3] += pv * w3;
        }
    };

    // prologue: 3 pairs in flight (9 VMEM ops per wave)
    issue_pair(0); issue_pair(1); issue_pair(2);

    f4 wf0, wf1, wf2, wf3;
    for (int g = 0; g < 99; ++g) {
        int p0 = 2 * g;
        // pair p0: own 3 ops done when <=6 outstanding (pairs p0+1, p0+2 in flight)
        SB0();
        asm volatile("s_waitcnt vmcnt(6)" ::: "memory");
        __builtin_amdgcn_s_barrier();
        SB0();
        issue_pair(p0 + 3);                   // target buf (p0+3)&3 = (p0-1)&3: last read at p0-1
        consume_pair(p0 & 3, wf0, wf1);

        SB0();
        asm volatile("s_waitcnt vmcnt(6)" ::: "memory");
        __builtin_amdgcn_s_barrier();
        SB0();
        if (g < 98) issue_pair(p0 + 4);       // pair 199 is the last (issued at g=98 first half)
        consume_pair((p0 + 1) & 3, wf2, wf3);

        contract(g, wf0, wf1, wf2, wf3);
    }
    // g = 99 peeled: pairs 198 (buf 2), 199 (buf 3); drain with exact counts
    SB0();
    asm volatile("s_waitcnt vmcnt(3)" ::: "memory");
    __builtin_amdgcn_s_barrier();
    SB0();
    consume_pair(2, wf0, wf1);
    SB0();
    asm volatile("s_waitcnt vmcnt(0)" ::: "memory");
    __builtin_amdgcn_s_barrier();
    SB0();
    consume_pair(3, wf2, wf3);
    contract(99, wf0, wf1, wf2, wf3);

    __syncthreads();   // all waves done reading sT/vT/pT -> reuse for output staging

    // out0 -> sT[e][c] (c = j*16 + q4*4 + r)
#pragma unroll
    for (int j = 0; j < 4; j++)
#pragma unroll
        for (int r = 0; r < 4; r++)
            sT[eln][j * 16 + q4 * 4 + r] = N0_CONST * acc0[j][r];
    // out1 -> vT flat [e*48 + wp*3 + i], wp = q4*4+r
    {
        float* vflat = (float*)vT;
        float s0v = sh0_s[eln];
        float s1v0 = sh1_s[0][eln], s1v1 = sh1_s[1][eln], s1v2 = sh1_s[2][eln];
#pragma unroll
        for (int r = 0; r < 4; r++) {
            int wp = q4 * 4 + r;
            vflat[eln * 48 + wp * 3 + 0] = N0_CONST * (accB[r] * s1v0 + accC[0][r] * s0v);
            vflat[eln * 48 + wp * 3 + 1] = N0_CONST * (accB[r] * s1v1 + accC[1][r] * s0v);
            vflat[eln * 48 + wp * 3 + 2] = N0_CONST * (accB[r] * s1v2 + accC[2][r] * s0v);
        }
    }
    __syncthreads();

    // single coalesced 28KB store of tp[e0..e0+64)[0..112) — nontemporal
    {
        const float* vflat = (const float*)vT;
        float* tpe = tp + (size_t)e0 * 112;
        for (int idx = tid; idx < 64 * 112; idx += 256) {
            int e = idx / 112;
            int c = idx - e * 112;
            float val = (c < 64) ? sT[e][c] : vflat[e * 48 + (c - 64)];
            __builtin_nontemporal_store(val, &tpe[idx]);
        }
    }
}

// Per-node segment mean over CSR edge list + residual. Block = node, thread = col.
__global__ __launch_bounds__(128) void k_red(const float* __restrict__ tp,
                                             const int* __restrict__ ptr,
                                             const int* __restrict__ eids,
                                             const float* __restrict__ node_attr,
                                             float* __restrict__ out) {
    int n = blockIdx.x;
    int c = threadIdx.x;
    if (c >= 112) return;
    int a = ptr[n], b = ptr[n + 1];
    float s = 0.f;
    for (int i = a; i < b; i++) {
        int e = eids[i];
        s += tp[(size_t)e * 112 + c];
    }
    float d = fmaxf((float)(b - a), 1.f);
    out[n * 112 + c] = s / d + node_attr[n * 112 + c];
}

extern "C" void kernel_launch(void* const* d_in, const int* in_sizes, int n_in,
                              void* d_out, int out_size, void* d_ws, size_t ws_size,
                              hipStream_t stream) {
    const float* node_attr  = (const float*)d_in[0];
    const int*   edge_index = (const int*)d_in[1];
    const float* edge_attr  = (const float*)d_in[2];
    const float* edge_sh    = (const float*)d_in[3];
    const float* W1         = (const float*)d_in[6];
    const float* b1         = (const float*)d_in[7];
    const float* W2         = (const float*)d_in[8];
    const float* b2         = (const float*)d_in[9];
    float* out = (float*)d_out;

    char* ws = (char*)d_ws;
    u16*   w2s    = (u16*)ws;                     // 6400*128*2  = 1,638,400
    u16*   w1t    = (u16*)(ws + 1638400);         // 128*128*2   =    32,768
    u16*   hgl    = (u16*)(ws + 1671168);         // 32768*128*2 = 8,388,608
    float* tp     = (float*)(ws + 10059776);      // 32768*112*4 = 14,680,064
    int*   deg    = (int*)(ws + 24739840);        // 4096*4
    int*   ptr    = (int*)(ws + 24756224);        // 4097*4
    int*   cursor = (int*)(ws + 24772624);        // 4096*4
    int*   eids   = (int*)(ws + 24789024);        // 32768*4

    hipMemsetAsync(deg, 0, 16384, stream);
    k_prep<<<544, 256, 0, stream>>>(W2, W1, edge_index, w2s, w1t, deg);
    k_scan<<<1, 64, 0, stream>>>(deg, ptr, cursor);
    k_h<<<512, 256, 0, stream>>>(edge_attr, w1t, b1, edge_index, cursor, eids, hgl);
    k_main<<<512, 256, 0, stream>>>(w2s, hgl, b2, node_attr, edge_index, edge_sh, tp);
    k_red<<<4096, 128, 0, stream>>>(tp, ptr, eids, node_attr, out);
}

// Round 4
// 196.259 us; speedup vs baseline: 1.2447x; 1.2163x over previous
//
#include <hip/hip_runtime.h>

typedef unsigned short u16;
typedef __bf16 bf8 __attribute__((ext_vector_type(8)));
typedef float f4 __attribute__((ext_vector_type(4)));

#define E_EDGES 32768
#define N_NODES 4096
// col layout of w (WNUM=6400): A[u<64][w<64] @0, B[u<64][w<16] @4096, C[u<16][w<16] @5120, D[u<16][w<64] @5376
// tile = 16 cols x 128 k = 4KB; group g covers tiles 4g..4g+3; A g<64, B 64..79, C 80..83, D 84..99
#define N0_CONST 0.1118033988749895f       // sqrt(1/80); also equals N1*INV_SQRT3
#define INV_SQRT3_CONST 0.5773502691896258f

__device__ __forceinline__ u16 f2bf(float f) {
    unsigned u = __float_as_uint(f);
    u += 0x7FFFu + ((u >> 16) & 1u);   // RNE
    return (u16)(u >> 16);
}

// Weight prep + src-degree histogram, one launch:
//  blocks 0..399:   w2s fragment-order swizzle (tile = 4KB contiguous)
//  blocks 400..415: w1t[c*128+k] = bf16(W1[k*128+c])
//  blocks 416..543: deg histogram over edge src (deg pre-zeroed by memsetAsync)
__global__ __launch_bounds__(256) void k_prep(const float* __restrict__ W2, const float* __restrict__ W1,
                                              const int* __restrict__ edge_index,
                                              u16* __restrict__ w2s, u16* __restrict__ w1t,
                                              int* __restrict__ deg) {
    int b = blockIdx.x;
    int tid = threadIdx.x;
    if (b < 400) {
        int ks = tid >> 6, l = tid & 63;
        int el = l & 15, q4 = l >> 4;
        int c = b * 16 + el;
        u16 tmp[8];
#pragma unroll
        for (int j = 0; j < 8; j++) {
            int k = ks * 32 + q4 * 8 + j;
            tmp[j] = f2bf(W2[(size_t)k * 6400 + c]);
        }
        *(uint4*)(w2s + b * 2048 + ks * 512 + l * 8) = *(uint4*)tmp;
    } else if (b < 416) {
        int t = (b - 400) * 256 + tid;
#pragma unroll
        for (int i = 0; i < 4; i++) {
            int idx = t * 4 + i;                // idx = c*128 + k
            int c = idx >> 7, k = idx & 127;
            w1t[idx] = f2bf(W1[k * 128 + c]);
        }
    } else {
        int t = (b - 416) * 256 + tid;          // 128 blocks * 256 = 32768 = E
        atomicAdd(&deg[edge_index[t]], 1);
    }
}

// Exclusive scan of deg[4096] -> ptr[0..4096] and cursor copy. 1 block, 64 threads.
__global__ void k_scan(const int* __restrict__ deg, int* __restrict__ ptr, int* __restrict__ cursor) {
    int t = threadIdx.x;           // 0..63
    int base = t * 64;
    int s = 0;
    for (int i = 0; i < 64; i++) s += deg[base + i];
    int x = s;
#pragma unroll
    for (int d = 1; d < 64; d <<= 1) {
        int y = __shfl_up(x, d, 64);
        if (t >= d) x += y;
    }
    int run = x - s;               // exclusive prefix
    for (int i = 0; i < 64; i++) {
        ptr[base + i] = run;
        cursor[base + i] = run;
        run += deg[base + i];
    }
    if (t == 63) ptr[4096] = run;
}

// h = relu(edge_attr @ W1 + b1), stored bf16 [E][128]; also fills CSR edge-id list via cursor
__global__ __launch_bounds__(256) void k_h(const float* __restrict__ ea,
                                           const u16* __restrict__ w1t,
                                           const float* __restrict__ b1,
                                           const int* __restrict__ edge_index,
                                           int* __restrict__ cursor,
                                           int* __restrict__ eids,
                                           u16* __restrict__ h) {
    __shared__ alignas(16) u16 ea_s[64][128];
    int tid = threadIdx.x;
    int e0 = blockIdx.x * 64;
    if (tid < 64) {                // CSR fill for this block's 64 edges
        int ge = e0 + tid;
        int s = edge_index[ge];
        int pos = atomicAdd(&cursor[s], 1);
        eids[pos] = ge;
    }
    {
        int e = tid >> 2, q = tid & 3;
        const float4* src = (const float4*)(ea + (size_t)(e0 + e) * 128 + q * 32);
#pragma unroll
        for (int i = 0; i < 8; i++) {
            float4 f = src[i];
            int c = q * 32 + i * 4;
            ea_s[e][c + 0] = f2bf(f.x); ea_s[e][c + 1] = f2bf(f.y);
            ea_s[e][c + 2] = f2bf(f.z); ea_s[e][c + 3] = f2bf(f.w);
        }
    }
    __syncthreads();
    int lane = tid & 63, wave = tid >> 6;
    int el = lane & 15, q4 = lane >> 4;
    f4 acc[4][2];
#pragma unroll
    for (int m = 0; m < 4; m++)
#pragma unroll
        for (int nt = 0; nt < 2; nt++) acc[m][nt] = (f4){0.f, 0.f, 0.f, 0.f};
#pragma unroll
    for (int ks = 0; ks < 4; ks++) {
        bf8 a[4], b[2];
#pragma unroll
        for (int m = 0; m < 4; m++) a[m] = *(const bf8*)&ea_s[m * 16 + el][ks * 32 + q4 * 8];
#pragma unroll
        for (int nt = 0; nt < 2; nt++) {
            int n = wave * 32 + nt * 16 + el;
            b[nt] = *(const bf8*)(w1t + n * 128 + ks * 32 + q4 * 8);
        }
#pragma unroll
        for (int m = 0; m < 4; m++)
#pragma unroll
            for (int nt = 0; nt < 2; nt++)
                acc[m][nt] = __builtin_amdgcn_mfma_f32_16x16x32_bf16(a[m], b[nt], acc[m][nt], 0, 0, 0);
    }
#pragma unroll
    for (int m = 0; m < 4; m++)
#pragma unroll
        for (int nt = 0; nt < 2; nt++) {
            int n = wave * 32 + nt * 16 + el;
            float bias = b1[n];
#pragma unroll
            for (int r = 0; r < 4; r++) {
                int e = e0 + m * 16 + q4 * 4 + r;
                float v = fmaxf(acc[m][nt][r] + bias, 0.f);
                h[(size_t)e * 128 + n] = f2bf(v);
            }
        }
}

// Fused: w = h@W2+b2 tile-by-tile -> contraction -> tp[E][112].
// ROUND-4 RESTRUCTURE (LDS-BW was the bottleneck: every wave read all 4 tiles -> 131KB/group/CU):
// wave owns ONE tile per group (its 16 w-cols) and computes ALL 64 edges (h for all 4 edge-groups
// in 64 VGPRs). Each tile consumed by exactly one wave -> A-fragments load GLOBAL->VGPR directly
// (double-buffered dwordx4, compiler-managed waits). Main loop: NO barriers, NO LDS tile traffic;
// only broadcast ds_read_b32 for contraction factors. B/C outputs (16 shared cols) are cross-wave
// partial sums -> combined via ds_add_f32 atomics into LDS scratch at phase ends.
// Loop order B(16) -> C(4) -> A(64) -> D(16) keeps accB/accC live ranges short (peak ~200 VGPR).
__global__ __launch_bounds__(256, 2) void k_main(const u16* __restrict__ w2s,
                                                 const u16* __restrict__ hgl,
                                                 const float* __restrict__ b2,
                                                 const float* __restrict__ node_attr,
                                                 const int* __restrict__ edge_index,
                                                 const float* __restrict__ edge_sh,
                                                 float* __restrict__ tp) {
    __shared__ alignas(16) union {
        u16 h[64][136];                               // 17408 B (prologue; +8 pad kills 16-way bank conflict)
        struct { float bcB[64][17]; float bcC[3][64][17]; } bc;   // 17408 B (B/C cross-wave sums)
    } ovl;
    __shared__ float sT[64][66];              // s[u][e]; epilogue: out0[e][c] (stride 66)
    __shared__ float vT[3][16][66];           // v[i][u][e]; epilogue: out1 flat [e*48+cr]
    __shared__ float pT[16][66];              // INV_SQRT3*(v.sh1)[u][e]
    __shared__ float sh0_s[64];
    __shared__ float sh1_s[3][64];
    __shared__ int dst_s[64];

    int tid = threadIdx.x;
    int e0 = blockIdx.x * 64;
    int lane = tid & 63, wave = tid >> 6;
    int el = lane & 15, q4 = lane >> 4;

    // A-fragment double buffer + per-tile bias; issued earliest for latency
    bf8 a0[4], a1[4];
    float4 bb0, bb1;
    auto loadA = [&](int i, bf8 (&a)[4], float4& bb) {
        int g = (i < 20) ? 64 + i : (i < 84 ? i - 20 : i);   // phase order B,C,A,D
        int pn = 4 * g + wave;
        const u16* gp = w2s + (size_t)pn * 2048 + lane * 8;
        a[0] = *(const bf8*)(gp);
        a[1] = *(const bf8*)(gp + 512);
        a[2] = *(const bf8*)(gp + 1024);
        a[3] = *(const bf8*)(gp + 1536);
        bb = *(const float4*)(b2 + pn * 16 + q4 * 4);
    };
    loadA(0, a0, bb0);   // prefetch first tile under the whole prologue

    // phase 1: edge meta
    if (tid < 64) {
        int ge = e0 + tid;
        dst_s[tid] = edge_index[E_EDGES + ge];
        float4 sh = *(const float4*)(edge_sh + (size_t)ge * 4);
        sh0_s[tid] = sh.x; sh1_s[0][tid] = sh.y; sh1_s[1][tid] = sh.z; sh1_s[2][tid] = sh.w;
    }
    __syncthreads();

    // phase 2: node features (transposed into LDS) + h tile into ovl.h
    {
        int e = tid >> 2, q = tid & 3;
        int dst = dst_s[e];
        const float* xp = node_attr + (size_t)dst * 112;
#pragma unroll
        for (int i = 0; i < 4; i++) {
            float4 f = *(const float4*)(xp + q * 16 + i * 4);
            int u = q * 16 + i * 4;
            sT[u + 0][e] = f.x; sT[u + 1][e] = f.y; sT[u + 2][e] = f.z; sT[u + 3][e] = f.w;
        }
        float vv[12];
#pragma unroll
        for (int i = 0; i < 3; i++) {
            float4 f = *(const float4*)(xp + 64 + q * 12 + i * 4);
            vv[i * 4 + 0] = f.x; vv[i * 4 + 1] = f.y; vv[i * 4 + 2] = f.z; vv[i * 4 + 3] = f.w;
        }
        float s1x = sh1_s[0][e], s1y = sh1_s[1][e], s1z = sh1_s[2][e];
#pragma unroll
        for (int u = 0; u < 4; u++) {
            float xa = vv[u * 3 + 0], xb = vv[u * 3 + 1], xc = vv[u * 3 + 2];
            int uu = q * 4 + u;
            vT[0][uu][e] = xa; vT[1][uu][e] = xb; vT[2][uu][e] = xc;
            pT[uu][e] = INV_SQRT3_CONST * (xa * s1x + xb * s1y + xc * s1z);
        }
        const uint4* hsrc = (const uint4*)(hgl + (size_t)(e0 + e) * 128) + q * 4;
        uint4* hdst = (uint4*)(&ovl.h[e][q * 32]);
#pragma unroll
        for (int i = 0; i < 4; i++) hdst[i] = hsrc[i];
    }
    __syncthreads();

    // h B-fragments for ALL 4 edge-groups (64 VGPRs) + per-lane sh0 factors
    bf8 hbf[4][4];
#pragma unroll
    for (int nt = 0; nt < 4; nt++)
#pragma unroll
        for (int ks = 0; ks < 4; ks++)
            hbf[nt][ks] = *(const bf8*)&ovl.h[nt * 16 + el][ks * 32 + q4 * 8];
    float sh0n4[4];
#pragma unroll
    for (int nt = 0; nt < 4; nt++) sh0n4[nt] = sh0_s[nt * 16 + el];
    __syncthreads();   // everyone done reading ovl.h -> becomes bc scratch

    // zero bc scratch (17408B = 4352 floats)
    for (int idx = tid; idx < 4352; idx += 256) ((float*)&ovl.bc)[idx] = 0.f;
    __syncthreads();   // bc zeroed before any wave's atomics

    auto mfmaG = [&](const bf8 (&a)[4], const float4& bb, f4 (&wf)[4]) {
#pragma unroll
        for (int nt = 0; nt < 4; nt++) wf[nt] = (f4){bb.x, bb.y, bb.z, bb.w};
#pragma unroll
        for (int ks = 0; ks < 4; ks++)
#pragma unroll
            for (int nt = 0; nt < 4; nt++)
                wf[nt] = __builtin_amdgcn_mfma_f32_16x16x32_bf16(a[ks], hbf[nt][ks], wf[nt], 0, 0, 0);
    };
    // result layout per lane: wf[nt][r] = w[edge = nt*16+el][col-in-tile = q4*4+r]

#define STEP(INXT, ACUR, BBCUR, ANXT, BBNXT, CON) \
    { if ((INXT) < 100) loadA((INXT), ANXT, BBNXT); mfmaG(ACUR, BBCUR, wf); CON; }

    f4 wf[4];

    // ---- B phase (i=0..15, g=64+i, u=4*i+wave; out col w = q4*4+r)
    {
        f4 accBn[4];
#pragma unroll
        for (int nt = 0; nt < 4; nt++) accBn[nt] = (f4){0.f, 0.f, 0.f, 0.f};
        auto conB = [&](int ib) {
            int u = 4 * ib + wave;
#pragma unroll
            for (int nt = 0; nt < 4; nt++) {
                float f = sT[u][nt * 16 + el];
                accBn[nt] += f * wf[nt];
            }
        };
        for (int ii = 0; ii < 16; ii += 2) {
            STEP(ii + 1, a0, bb0, a1, bb1, conB(ii));
            STEP(ii + 2, a1, bb1, a0, bb0, conB(ii + 1));
        }
#pragma unroll
        for (int nt = 0; nt < 4; nt++)
#pragma unroll
            for (int r = 0; r < 4; r++)
                atomicAdd(&ovl.bc.bcB[nt * 16 + el][q4 * 4 + r], accBn[nt][r]);
    }

    // ---- C phase (i=16..19, g=80+(i-16), u=4*(i-16)+wave)
    {
        f4 accCn[3][4];
#pragma unroll
        for (int i3 = 0; i3 < 3; i3++)
#pragma unroll
            for (int nt = 0; nt < 4; nt++) accCn[i3][nt] = (f4){0.f, 0.f, 0.f, 0.f};
        auto conC = [&](int ic) {
            int u = 4 * ic + wave;
#pragma unroll
            for (int nt = 0; nt < 4; nt++) {
#pragma unroll
                for (int i3 = 0; i3 < 3; i3++) {
                    float f = vT[i3][u][nt * 16 + el];
                    accCn[i3][nt] += f * wf[nt];
                }
            }
        };
        for (int ii = 0; ii < 4; ii += 2) {
            STEP(16 + ii + 1, a0, bb0, a1, bb1, conC(ii));
            STEP(16 + ii + 2, a1, bb1, a0, bb0, conC(ii + 1));
        }
#pragma unroll
        for (int i3 = 0; i3 < 3; i3++)
#pragma unroll
            for (int nt = 0; nt < 4; nt++)
#pragma unroll
                for (int r = 0; r < 4; r++)
                    atomicAdd(&ovl.bc.bcC[i3][nt * 16 + el][q4 * 4 + r], accCn[i3][nt][r]);
    }

    // ---- A phase (i=20..83, g=i-20=u) then D phase (i=84..99, u=i-84); both -> acc0n
    f4 acc0n[4];
#pragma unroll
    for (int nt = 0; nt < 4; nt++) acc0n[nt] = (f4){0.f, 0.f, 0.f, 0.f};
    {
        auto conA = [&](int ia) {
#pragma unroll
            for (int nt = 0; nt < 4; nt++) {
                float f = sh0n4[nt] * sT[ia][nt * 16 + el];
                acc0n[nt] += f * wf[nt];
            }
        };
        for (int ii = 0; ii < 64; ii += 2) {
            STEP(20 + ii + 1, a0, bb0, a1, bb1, conA(ii));
            STEP(20 + ii + 2, a1, bb1, a0, bb0, conA(ii + 1));
        }
        auto conD = [&](int id_) {
#pragma unroll
            for (int nt = 0; nt < 4; nt++) {
                float f = pT[id_][nt * 16 + el];
                acc0n[nt] += f * wf[nt];
            }
        };
        for (int ii = 0; ii < 16; ii += 2) {
            STEP(84 + ii + 1, a0, bb0, a1, bb1, conD(ii));
            STEP(84 + ii + 2, a1, bb1, a0, bb0, conD(ii + 1));
        }
    }
#undef STEP

    __syncthreads();   // loop reads of sT/vT/pT done; all bc atomics landed

    // out0 -> sT[e][c]: wave owns col block wave*16 (A/D cols), all 64 edges
#pragma unroll
    for (int nt = 0; nt < 4; nt++)
#pragma unroll
        for (int r = 0; r < 4; r++)
            sT[nt * 16 + el][wave * 16 + q4 * 4 + r] = N0_CONST * acc0n[nt][r];
    // out1 assembly from bc sums -> vflat [e*48 + w*3 + i]
    {
        float* vflat = (float*)vT;
        for (int idx = tid; idx < 3072; idx += 256) {
            int e = idx / 48;
            int rem = idx - e * 48;
            int w = rem / 3;
            int i3 = rem - w * 3;
            vflat[idx] = N0_CONST * (ovl.bc.bcB[e][w] * sh1_s[i3][e] + ovl.bc.bcC[i3][e][w] * sh0_s[e]);
        }
    }
    __syncthreads();

    // single coalesced 28KB store of tp[e0..e0+64)[0..112) — nontemporal
    {
        const float* vflat = (const float*)vT;
        float* tpe = tp + (size_t)e0 * 112;
        for (int idx = tid; idx < 64 * 112; idx += 256) {
            int e = idx / 112;
            int c = idx - e * 112;
            float val = (c < 64) ? sT[e][c] : vflat[e * 48 + (c - 64)];
            __builtin_nontemporal_store(val, &tpe[idx]);
        }
    }
}

// Per-node segment mean over CSR edge list + residual. Block = node, thread = col.
__global__ __launch_bounds__(128) void k_red(const float* __restrict__ tp,
                                             const int* __restrict__ ptr,
                                             const int* __restrict__ eids,
                                             const float* __restrict__ node_attr,
                                             float* __restrict__ out) {
    int n = blockIdx.x;
    int c = threadIdx.x;
    if (c >= 112) return;
    int a = ptr[n], b = ptr[n + 1];
    float s = 0.f;
    for (int i = a; i < b; i++) {
        int e = eids[i];
        s += tp[(size_t)e * 112 + c];
    }
    float d = fmaxf((float)(b - a), 1.f);
    out[n * 112 + c] = s / d + node_attr[n * 112 + c];
}

extern "C" void kernel_launch(void* const* d_in, const int* in_sizes, int n_in,
                              void* d_out, int out_size, void* d_ws, size_t ws_size,
                              hipStream_t stream) {
    const float* node_attr  = (const float*)d_in[0];
    const int*   edge_index = (const int*)d_in[1];
    const float* edge_attr  = (const float*)d_in[2];
    const float* edge_sh    = (const float*)d_in[3];
    const float* W1         = (const float*)d_in[6];
    const float* b1         = (const float*)d_in[7];
    const float* W2         = (const float*)d_in[8];
    const float* b2         = (const float*)d_in[9];
    float* out = (float*)d_out;

    char* ws = (char*)d_ws;
    u16*   w2s    = (u16*)ws;                     // 6400*128*2  = 1,638,400
    u16*   w1t    = (u16*)(ws + 1638400);         // 128*128*2   =    32,768
    u16*   hgl    = (u16*)(ws + 1671168);         // 32768*128*2 = 8,388,608
    float* tp     = (float*)(ws + 10059776);      // 32768*112*4 = 14,680,064
    int*   deg    = (int*)(ws + 24739840);        // 4096*4
    int*   ptr    = (int*)(ws + 24756224);        // 4097*4
    int*   cursor = (int*)(ws + 24772624);        // 4096*4
    int*   eids   = (int*)(ws + 24789024);        // 32768*4

    hipMemsetAsync(deg, 0, 16384, stream);
    k_prep<<<544, 256, 0, stream>>>(W2, W1, edge_index, w2s, w1t, deg);
    k_scan<<<1, 64, 0, stream>>>(deg, ptr, cursor);
    k_h<<<512, 256, 0, stream>>>(edge_attr, w1t, b1, edge_index, cursor, eids, hgl);
    k_main<<<512, 256, 0, stream>>>(w2s, hgl, b2, node_attr, edge_index, edge_sh, tp);
    k_red<<<4096, 128, 0, stream>>>(tp, ptr, eids, node_attr, out);
}